// Round 7
// baseline (554.422 us; speedup 1.0000x reference)
//
#include <hip/hip_runtime.h>
#include <hip/hip_fp16.h>

#define N_NODES 100000
#define N_EDGES 1600000
#define E_TOT   (N_EDGES + N_NODES)   // 1,700,000 incl. self-loops
#define NEG_SLOPE 0.2f
#define NB1 ((N_NODES + 255) / 256)   // 391 scan blocks
#define PART_EPB 4096                 // edges per k_part block
#define BSTRIDE 18432                 // slots per bucket region (mean 17408 + 7.8 sigma; input is fixed -> deterministic)
#define FILL_CPB 72                   // fill2 chunks per bucket (72*256 = 18432)

// ---------------------------------------------------------------------------
// k_part: single pass over ei. Counts per-node degree (was k_hist) AND
// partitions edges into 128 fixed-stride dst-buckets (dst>>10). Bucket
// regions are padded (BSTRIDE) so no scan dependency.
// ---------------------------------------------------------------------------
__global__ __launch_bounds__(256)
void k_part(const int* __restrict__ ei, int* __restrict__ deg,
            int* __restrict__ bcnt, int2* __restrict__ pairs) {
    const int t = threadIdx.x;
    const int base = blockIdx.x * PART_EPB;
    __shared__ int lcnt[128];
    __shared__ int lbase[128];
    if (t < 128) lcnt[t] = 0;
    __syncthreads();
    int sr[16], dr[16];
#pragma unroll
    for (int u = 0; u < 16; ++u) {
        const int e = base + u * 256 + t;    // coalesced
        if (e < E_TOT) {
            int s, d;
            if (e < N_EDGES) { s = ei[e]; d = ei[N_EDGES + e]; }
            else             { s = d = e - N_EDGES; }
            sr[u] = s; dr[u] = d;
            atomicAdd(&deg[d], 1);           // degree histogram (was k_hist)
            atomicAdd(&lcnt[d >> 10], 1);
        } else dr[u] = -1;
    }
    __syncthreads();
    if (t < 128) {
        const int c = lcnt[t];
        lbase[t] = (c > 0) ? atomicAdd(&bcnt[t], c) : 0;
        lcnt[t] = 0;                         // reuse as local cursor
    }
    __syncthreads();
#pragma unroll
    for (int u = 0; u < 16; ++u) {
        if (dr[u] >= 0) {
            const int bk = dr[u] >> 10;
            const int r = atomicAdd(&lcnt[bk], 1);
            pairs[(size_t)bk * BSTRIDE + lbase[bk] + r] = make_int2(sr[u], dr[u]);
        }
    }
}

// ---------------------------------------------------------------------------
// Exclusive scan over degrees -> CSR offsets.
// ---------------------------------------------------------------------------
__global__ __launch_bounds__(256)
void k_scan1(const int* __restrict__ deg, int* __restrict__ part, int* __restrict__ bsums) {
    __shared__ int buf[256];
    const int t = threadIdx.x;
    const int i = blockIdx.x * 256 + t;
    int v = (i < N_NODES) ? deg[i] : 0;
    buf[t] = v;
    __syncthreads();
    for (int off = 1; off < 256; off <<= 1) {
        int add = (t >= off) ? buf[t - off] : 0;
        __syncthreads();
        buf[t] += add;
        __syncthreads();
    }
    if (i < N_NODES) part[i] = buf[t] - v;   // exclusive within block
    if (t == 255) bsums[blockIdx.x] = buf[255];
}

__global__ __launch_bounds__(512)
void k_scan2(int* __restrict__ bsums) {
    __shared__ int buf[512];
    const int t = threadIdx.x;
    int v = (t < NB1) ? bsums[t] : 0;
    buf[t] = v;
    __syncthreads();
    for (int off = 1; off < 512; off <<= 1) {
        int add = (t >= off) ? buf[t - off] : 0;
        __syncthreads();
        buf[t] += add;
        __syncthreads();
    }
    if (t < NB1) bsums[t] = buf[t] - v;      // exclusive block offsets
}

__global__ __launch_bounds__(256)
void k_scan3(int* __restrict__ offs, const int* __restrict__ bsums, int* __restrict__ cur) {
    const int i = blockIdx.x * blockDim.x + threadIdx.x;
    if (i >= N_NODES) return;
    const int o = offs[i] + bsums[i >> 8];
    offs[i] = o;
    cur[i] = o;
}

// ---------------------------------------------------------------------------
// k_fill2: bucket-grouped fine fill (XCD swizzle keeps each bucket's ssrc/ew
// region on one XCD's L2 -> full-line writebacks). Also precomputes the 4
// per-edge softmax weights exp(leaky(al1[s]+ar1[d])) into fp16 ew[pos] so
// the hot aggregation loop needs no weight phase at all.
// ---------------------------------------------------------------------------
__global__ __launch_bounds__(256)
void k_fill2(const int2* __restrict__ pairs, const int* __restrict__ bcnt,
             const float* __restrict__ al1, const float* __restrict__ ar1,
             int* __restrict__ cur, int* __restrict__ ssrc, __half* __restrict__ ew) {
    // grid = 128 buckets * FILL_CPB chunks = 9216 (multiple of 8)
    const int nb8 = (128 * FILL_CPB) >> 3;
    const int vb = (blockIdx.x & 7) * nb8 + (blockIdx.x >> 3);
    const int bucket = vb / FILL_CPB;
    const int chunk = vb - bucket * FILL_CPB;
    const int i = chunk * 256 + (int)threadIdx.x;
    if (i >= bcnt[bucket]) return;
    const int2 p = pairs[(size_t)bucket * BSTRIDE + i];
    const int pos = atomicAdd(&cur[p.y], 1);
    ssrc[pos] = p.x;
    const float4 al = ((const float4*)al1)[p.x];
    const float4 ar = ((const float4*)ar1)[p.y];
    float v0 = al.x + ar.x; v0 = v0 > 0.f ? v0 : NEG_SLOPE * v0;
    float v1 = al.y + ar.y; v1 = v1 > 0.f ? v1 : NEG_SLOPE * v1;
    float v2 = al.z + ar.z; v2 = v2 > 0.f ? v2 : NEG_SLOPE * v2;
    float v3 = al.w + ar.w; v3 = v3 > 0.f ? v3 : NEG_SLOPE * v3;
    __half hw[4];
    hw[0] = __float2half(__expf(v0));
    hw[1] = __float2half(__expf(v1));
    hw[2] = __float2half(__expf(v2));
    hw[3] = __float2half(__expf(v3));
    *(uint2*)&ew[(size_t)pos * 4] = *(uint2*)hw;
}

// ---------------------------------------------------------------------------
// Layer 1 GEMM, register-tiled: 256 threads, 32 nodes/block, 4x4 tile/thread.
// fp32 math; xw1 stored fp16.
// ---------------------------------------------------------------------------
__global__ __launch_bounds__(256)
void k_gemm1(const float* __restrict__ x, const float* __restrict__ W1,
             const float* __restrict__ a_src1, const float* __restrict__ a_dst1,
             __half* __restrict__ xw1h, float* __restrict__ al1, float* __restrict__ ar1) {
    const int t = threadIdx.x;
    const int n0 = blockIdx.x * 32;
    __shared__ float sx[32][128];   // 16 KB
    __shared__ float sW[32][128];   // 16 KB (one 32-row k-tile of W1)

    {   // stage x tile: 1024 float4s, coalesced
        const float4* xg = (const float4*)(x + (size_t)n0 * 128);
#pragma unroll
        for (int i = 0; i < 4; ++i) {
            const int f = t + i * 256;
            ((float4*)sx)[f] = xg[f];
        }
    }

    const int tj = t & 31;          // column group: cols 4*tj .. 4*tj+3
    const int tn = (t >> 5) * 4;    // node group:   nodes tn .. tn+3
    float4 acc[4] = {{0,0,0,0},{0,0,0,0},{0,0,0,0},{0,0,0,0}};

    for (int kt = 0; kt < 128; kt += 32) {
        __syncthreads();
        const float4* wg = (const float4*)(W1 + (size_t)kt * 128);
#pragma unroll
        for (int i = 0; i < 4; ++i) {
            const int f = t + i * 256;
            ((float4*)sW)[f] = wg[f];
        }
        __syncthreads();
        for (int k = 0; k < 32; k += 4) {
            float4 xv[4];
#pragma unroll
            for (int i = 0; i < 4; ++i)
                xv[i] = *(const float4*)&sx[tn + i][kt + k];   // broadcast reads
#pragma unroll
            for (int kk = 0; kk < 4; ++kk) {
                const float4 wv = *(const float4*)&sW[k + kk][tj * 4];
#pragma unroll
                for (int i = 0; i < 4; ++i) {
                    const float xs = ((const float*)&xv[i])[kk];
                    acc[i].x = fmaf(xs, wv.x, acc[i].x);
                    acc[i].y = fmaf(xs, wv.y, acc[i].y);
                    acc[i].z = fmaf(xs, wv.z, acc[i].z);
                    acc[i].w = fmaf(xs, wv.w, acc[i].w);
                }
            }
        }
    }

    // write xw1 as fp16 (4 halves = 8B store, aligned)
#pragma unroll
    for (int i = 0; i < 4; ++i) {
        __half hp[4];
        hp[0] = __float2half(acc[i].x);
        hp[1] = __float2half(acc[i].y);
        hp[2] = __float2half(acc[i].z);
        hp[3] = __float2half(acc[i].w);
        *(uint2*)&xw1h[(size_t)(n0 + tn + i) * 128 + tj * 4] = *(uint2*)hp;
    }

    // fused attention dots (fp32): head h = tj>>3
    const float4 asv = ((const float4*)a_src1)[tj];
    const float4 adv = ((const float4*)a_dst1)[tj];
#pragma unroll
    for (int i = 0; i < 4; ++i) {
        float ps = acc[i].x * asv.x + acc[i].y * asv.y + acc[i].z * asv.z + acc[i].w * asv.w;
        float pd = acc[i].x * adv.x + acc[i].y * adv.y + acc[i].z * adv.z + acc[i].w * adv.w;
#pragma unroll
        for (int o = 1; o < 8; o <<= 1) { ps += __shfl_xor(ps, o, 64); pd += __shfl_xor(pd, o, 64); }
        if ((tj & 7) == 0) {
            const int h = tj >> 3;
            al1[(size_t)(n0 + tn + i) * 4 + h] = ps;
            ar1[(size_t)(n0 + tn + i) * 4 + h] = pd;
        }
    }
}

// ---------------------------------------------------------------------------
// Layer 1 pull-aggregation v3: one WAVE per dst node, zero barriers.
// Lane = g*16+c: 4 edge-groups x 16 col-lanes; each lane gathers uint4
// (8 halves, 16B) -> one wave-load moves 4 full rows. Weights come
// precomputed from ew (sequential, L1-hot). 8 edges in flight per wave.
// Shuffle-only cross-group reduction; fused /denom + b1 + ReLU, fp16 out.
// ---------------------------------------------------------------------------
__global__ __launch_bounds__(256)
void k_aggr1(const int* __restrict__ ssrc, const int* __restrict__ offs,
             const int* __restrict__ deg, const __half* __restrict__ ew,
             const __half* __restrict__ xw1h, const float* __restrict__ b1,
             __half* __restrict__ out1h) {
    const int lane = threadIdx.x & 63;
    const int d = blockIdx.x * 4 + (threadIdx.x >> 6);
    const int g = lane >> 4;                 // edge group 0..3
    const int c = lane & 15;                 // col group: features 8c..8c+7
    const int h = c >> 2;                    // head of this col group
    const int beg = offs[d];
    const int n = deg[d];
    float acc[8] = {0.f, 0.f, 0.f, 0.f, 0.f, 0.f, 0.f, 0.f};
    float dnm = 0.f;

    for (int base = 0; base < n; base += 8) {
#pragma unroll
        for (int u = 0; u < 2; ++u) {
            const int e = base + u * 4 + g;
            const bool p = e < n;
            const int idx = beg + (p ? e : 0);
            const int s = ssrc[idx];                       // L1-hot (sequential)
            const float w = p ? __half2float(ew[(size_t)idx * 4 + h]) : 0.f;
            const uint4 rv = *(const uint4*)&xw1h[(size_t)s * 128 + c * 8];
            const float2 f0 = __half22float2(*(const __half2*)&rv.x);
            const float2 f1 = __half22float2(*(const __half2*)&rv.y);
            const float2 f2 = __half22float2(*(const __half2*)&rv.z);
            const float2 f3 = __half22float2(*(const __half2*)&rv.w);
            acc[0] = fmaf(w, f0.x, acc[0]); acc[1] = fmaf(w, f0.y, acc[1]);
            acc[2] = fmaf(w, f1.x, acc[2]); acc[3] = fmaf(w, f1.y, acc[3]);
            acc[4] = fmaf(w, f2.x, acc[4]); acc[5] = fmaf(w, f2.y, acc[5]);
            acc[6] = fmaf(w, f3.x, acc[6]); acc[7] = fmaf(w, f3.y, acc[7]);
            dnm += w;
        }
    }
    // reduce across the 4 edge-groups (g lives in lane bits 4..5)
#pragma unroll
    for (int i = 0; i < 8; ++i) {
        acc[i] += __shfl_xor(acc[i], 16, 64);
        acc[i] += __shfl_xor(acc[i], 32, 64);
    }
    dnm += __shfl_xor(dnm, 16, 64);
    dnm += __shfl_xor(dnm, 32, 64);
    if (g == 0) {
        const float rc = 1.f / dnm;
        const float4 b01 = *(const float4*)&b1[c * 8];
        const float4 b23 = *(const float4*)&b1[c * 8 + 4];
        const float bb[8] = {b01.x, b01.y, b01.z, b01.w, b23.x, b23.y, b23.z, b23.w};
        __half ho[8];
#pragma unroll
        for (int i = 0; i < 8; ++i) {
            const float hv = acc[i] * rc + bb[i];
            ho[i] = __float2half(hv > 0.f ? hv : 0.f);     // bias + ReLU
        }
        *(uint4*)&out1h[(size_t)d * 128 + c * 8] = *(uint4*)ho;
    }
}

// ---------------------------------------------------------------------------
// Layer 2 GEMM: 16 nodes/block, 256 threads. Reads fp16 out1, fp32 math,
// xw2 stored fp16, al2/ar2 fp32.
// ---------------------------------------------------------------------------
__global__ __launch_bounds__(256)
void k_gemm2(const __half* __restrict__ out1h, const float* __restrict__ W2,
             const float* __restrict__ a_src2, const float* __restrict__ a_dst2,
             __half* __restrict__ xw2h, float* __restrict__ al2, float* __restrict__ ar2) {
    const int t = threadIdx.x;
    const int node0 = blockIdx.x * 16;
    __shared__ float sW[128 * 16];
    __shared__ float sh[16][129];            // +1 pad: kills 4-way bank conflict
    for (int i = t; i < 2048; i += 256) sW[i] = W2[i];
    for (int i = t; i < 2048; i += 256) {
        const int nn = i >> 7, kk = i & 127;
        sh[nn][kk] = __half2float(out1h[(size_t)(node0 + nn) * 128 + kk]);
    }
    __syncthreads();
    const int nn = t >> 4;                   // 0..15
    const int j = t & 15;
    float acc = 0.f;
#pragma unroll 8
    for (int k = 0; k < 128; ++k)
        acc = fmaf(sh[nn][k], sW[k * 16 + j], acc);
    xw2h[(size_t)(node0 + nn) * 16 + j] = __float2half(acc);

    float ps = acc * a_src2[j];
    float pd = acc * a_dst2[j];
#pragma unroll
    for (int o = 8; o; o >>= 1) { ps += __shfl_xor(ps, o, 64); pd += __shfl_xor(pd, o, 64); }
    if (j == 0) { al2[node0 + nn] = ps; ar2[node0 + nn] = pd; }
}

// ---------------------------------------------------------------------------
// Layer 2 pull-aggregation: one wave per node; 8 edge-groups x 8 half2
// feature-lanes. Cross-group shuffle reduction, fused +b2.
// ---------------------------------------------------------------------------
__global__ __launch_bounds__(256)
void k_aggr2(const int* __restrict__ ssrc, const int* __restrict__ offs,
             const int* __restrict__ deg, const float* __restrict__ al2,
             const float* __restrict__ ar2, const __half* __restrict__ xw2h,
             const float* __restrict__ b2, float* __restrict__ out) {
    const int lane = threadIdx.x & 63;
    const int node = blockIdx.x * 4 + (threadIdx.x >> 6);
    const int j2 = lane & 7;                 // feature pair 2*j2, 2*j2+1
    const int eL = lane >> 3;                // 0..7
    const int beg = offs[node];
    const int n = deg[node];
    const float ard = ar2[node];
    float a0 = 0.f, a1 = 0.f, dnm = 0.f;
    for (int base = 0; base < n; base += 8) {
        const int e = base + eL;
        const bool p = e < n;
        const int s = ssrc[beg + (p ? e : 0)];
        float v = al2[s] + ard;
        v = v > 0.f ? v : NEG_SLOPE * v;
        const float w = p ? __expf(v) : 0.f;
        const float2 f = __half22float2(*(const __half2*)&xw2h[(size_t)s * 16 + j2 * 2]);
        a0 = fmaf(w, f.x, a0);
        a1 = fmaf(w, f.y, a1);
        dnm += w;
    }
#pragma unroll
    for (int o = 8; o < 64; o <<= 1) {
        a0 += __shfl_xor(a0, o, 64);
        a1 += __shfl_xor(a1, o, 64);
        dnm += __shfl_xor(dnm, o, 64);
    }
    if (eL == 0) {
        out[(size_t)node * 16 + j2 * 2]     = a0 / dnm + b2[j2 * 2];
        out[(size_t)node * 16 + j2 * 2 + 1] = a1 / dnm + b2[j2 * 2 + 1];
    }
}

extern "C" void kernel_launch(void* const* d_in, const int* in_sizes, int n_in,
                              void* d_out, int out_size, void* d_ws, size_t ws_size,
                              hipStream_t stream) {
    const float* x      = (const float*)d_in[0];
    const int*   ei     = (const int*)d_in[1];
    const float* W1     = (const float*)d_in[2];
    const float* a_src1 = (const float*)d_in[3];
    const float* a_dst1 = (const float*)d_in[4];
    const float* b1     = (const float*)d_in[5];
    const float* W2     = (const float*)d_in[6];
    const float* a_src2 = (const float*)d_in[7];
    const float* a_dst2 = (const float*)d_in[8];
    const float* b2     = (const float*)d_in[9];
    float* out = (float*)d_out;

    // Workspace (byte-addressed). Aliases:
    //  - pairs (18.9MB) sits in out1h's region (25.6MB): consumed by k_fill2
    //    before k_aggr1 writes out1h.
    //  - xw2h/al2/ar2 sit in xw1h's region: written by k_gemm2 after k_aggr1
    //    is done with xw1h.
    char* wsb = (char*)d_ws;
    __half* xw1h = (__half*)wsb;                                  // N*128 half (25.6 MB)
    __half* xw2h = (__half*)wsb;                                  // N*16 half (alias)
    float*  al2  = (float*)(wsb + (size_t)N_NODES * 16 * 2);      // N fp32 (alias)
    float*  ar2  = al2 + N_NODES;                                 // N fp32 (alias)
    __half* out1h = (__half*)(wsb + (size_t)N_NODES * 128 * 2);   // N*128 half (25.6 MB)
    int2*   pairs = (int2*)out1h;                                 // 128*BSTRIDE int2 (alias, 18.9 MB)
    float*  al1  = (float*)(wsb + (size_t)N_NODES * 128 * 4);     // N*4 fp32
    float*  ar1  = al1 + (size_t)N_NODES * 4;                     // N*4
    int* ideg  = (int*)(ar1 + (size_t)N_NODES * 4);               // N      } zeroed together
    int* ibcnt = ideg + N_NODES;                                  // 128    } zeroed together
    int* ioff  = ibcnt + 128;                                     // N
    int* icur  = ioff + N_NODES;                                  // N
    int* ibs   = icur + N_NODES;                                  // 512
    int* isrc  = ibs + 512;                                       // E_TOT
    __half* ew = (__half*)(isrc + E_TOT);                         // E_TOT*4 half (13.6 MB)

    hipMemsetAsync(ideg, 0, ((size_t)N_NODES + 128) * sizeof(int), stream);

    // CSR build: part (deg histogram + bucket partition) -> scan -> fill.
    k_part<<<(E_TOT + PART_EPB - 1) / PART_EPB, 256, 0, stream>>>(ei, ideg, ibcnt, pairs);
    k_scan1<<<NB1, 256, 0, stream>>>(ideg, ioff, ibs);
    k_scan2<<<1, 512, 0, stream>>>(ibs);
    k_scan3<<<NB1, 256, 0, stream>>>(ioff, ibs, icur);

    // Layer-1 GEMM before fill2 (fill2 consumes al1/ar1 for edge weights).
    k_gemm1<<<N_NODES / 32, 256, 0, stream>>>(x, W1, a_src1, a_dst1, xw1h, al1, ar1);
    k_fill2<<<128 * FILL_CPB, 256, 0, stream>>>(pairs, ibcnt, al1, ar1, icur, isrc, ew);

    // Layer 1 aggregation
    k_aggr1<<<N_NODES / 4, 256, 0, stream>>>(isrc, ioff, ideg, ew, xw1h, b1, out1h);

    // Layer 2
    k_gemm2<<<N_NODES / 16, 256, 0, stream>>>(out1h, W2, a_src2, a_dst2, xw2h, al2, ar2);
    k_aggr2<<<N_NODES / 4, 256, 0, stream>>>(isrc, ioff, ideg, al2, ar2, xw2h, b2, out);
}

// Round 8
// 546.800 us; speedup vs baseline: 1.0139x; 1.0139x over previous
//
#include <hip/hip_runtime.h>
#include <hip/hip_fp16.h>

#define N_NODES 100000
#define N_EDGES 1600000
#define E_TOT   (N_EDGES + N_NODES)   // 1,700,000 incl. self-loops
#define NEG_SLOPE 0.2f
#define NB1 ((N_NODES + 255) / 256)   // 391 scan blocks
#define PART_EPB 4096                 // edges per k_part block
#define BSTRIDE 18432                 // slots per bucket region (mean 17408 + 7.8 sigma; fixed input -> deterministic)
#define FILL_CPB 72                   // fill2 chunks per bucket (72*256 = 18432)

// ---------------------------------------------------------------------------
// k_part: single pass over ei. Counts per-node degree AND partitions edges
// into 128 fixed-stride dst-buckets (dst>>10). Padded regions -> no scan dep.
// ---------------------------------------------------------------------------
__global__ __launch_bounds__(256)
void k_part(const int* __restrict__ ei, int* __restrict__ deg,
            int* __restrict__ bcnt, int2* __restrict__ pairs) {
    const int t = threadIdx.x;
    const int base = blockIdx.x * PART_EPB;
    __shared__ int lcnt[128];
    __shared__ int lbase[128];
    if (t < 128) lcnt[t] = 0;
    __syncthreads();
    int sr[16], dr[16];
#pragma unroll
    for (int u = 0; u < 16; ++u) {
        const int e = base + u * 256 + t;    // coalesced
        if (e < E_TOT) {
            int s, d;
            if (e < N_EDGES) { s = ei[e]; d = ei[N_EDGES + e]; }
            else             { s = d = e - N_EDGES; }
            sr[u] = s; dr[u] = d;
            atomicAdd(&deg[d], 1);           // degree histogram
            atomicAdd(&lcnt[d >> 10], 1);
        } else dr[u] = -1;
    }
    __syncthreads();
    if (t < 128) {
        const int c = lcnt[t];
        lbase[t] = (c > 0) ? atomicAdd(&bcnt[t], c) : 0;
        lcnt[t] = 0;                         // reuse as local cursor
    }
    __syncthreads();
#pragma unroll
    for (int u = 0; u < 16; ++u) {
        if (dr[u] >= 0) {
            const int bk = dr[u] >> 10;
            const int r = atomicAdd(&lcnt[bk], 1);
            pairs[(size_t)bk * BSTRIDE + lbase[bk] + r] = make_int2(sr[u], dr[u]);
        }
    }
}

// ---------------------------------------------------------------------------
// Exclusive scan over degrees -> CSR offsets.
// ---------------------------------------------------------------------------
__global__ __launch_bounds__(256)
void k_scan1(const int* __restrict__ deg, int* __restrict__ part, int* __restrict__ bsums) {
    __shared__ int buf[256];
    const int t = threadIdx.x;
    const int i = blockIdx.x * 256 + t;
    int v = (i < N_NODES) ? deg[i] : 0;
    buf[t] = v;
    __syncthreads();
    for (int off = 1; off < 256; off <<= 1) {
        int add = (t >= off) ? buf[t - off] : 0;
        __syncthreads();
        buf[t] += add;
        __syncthreads();
    }
    if (i < N_NODES) part[i] = buf[t] - v;   // exclusive within block
    if (t == 255) bsums[blockIdx.x] = buf[255];
}

__global__ __launch_bounds__(512)
void k_scan2(int* __restrict__ bsums) {
    __shared__ int buf[512];
    const int t = threadIdx.x;
    int v = (t < NB1) ? bsums[t] : 0;
    buf[t] = v;
    __syncthreads();
    for (int off = 1; off < 512; off <<= 1) {
        int add = (t >= off) ? buf[t - off] : 0;
        __syncthreads();
        buf[t] += add;
        __syncthreads();
    }
    if (t < NB1) bsums[t] = buf[t] - v;      // exclusive block offsets
}

__global__ __launch_bounds__(256)
void k_scan3(int* __restrict__ offs, const int* __restrict__ bsums, int* __restrict__ cur) {
    const int i = blockIdx.x * blockDim.x + threadIdx.x;
    if (i >= N_NODES) return;
    const int o = offs[i] + bsums[i >> 8];
    offs[i] = o;
    cur[i] = o;
}

// ---------------------------------------------------------------------------
// k_fill2: bucket-grouped fine fill, minimal work (R7 post-mortem: adding
// per-edge weight production here cost +150us in scattered stores). XCD
// swizzle keeps each bucket's ssrc region L2-local -> full-line writebacks.
// ---------------------------------------------------------------------------
__global__ __launch_bounds__(256)
void k_fill2(const int2* __restrict__ pairs, const int* __restrict__ bcnt,
             int* __restrict__ cur, int* __restrict__ ssrc) {
    // grid = 128 buckets * FILL_CPB chunks = 9216 (multiple of 8)
    const int nb8 = (128 * FILL_CPB) >> 3;
    const int vb = (blockIdx.x & 7) * nb8 + (blockIdx.x >> 3);
    const int bucket = vb / FILL_CPB;
    const int chunk = vb - bucket * FILL_CPB;
    const int i = chunk * 256 + (int)threadIdx.x;
    if (i >= bcnt[bucket]) return;
    const int2 p = pairs[(size_t)bucket * BSTRIDE + i];
    const int pos = atomicAdd(&cur[p.y], 1);
    ssrc[pos] = p.x;
}

// ---------------------------------------------------------------------------
// Layer 1 GEMM, register-tiled: 256 threads, 32 nodes/block, 4x4 tile/thread.
// fp32 math; xw1 stored fp16.
// ---------------------------------------------------------------------------
__global__ __launch_bounds__(256)
void k_gemm1(const float* __restrict__ x, const float* __restrict__ W1,
             const float* __restrict__ a_src1, const float* __restrict__ a_dst1,
             __half* __restrict__ xw1h, float* __restrict__ al1, float* __restrict__ ar1) {
    const int t = threadIdx.x;
    const int n0 = blockIdx.x * 32;
    __shared__ float sx[32][128];   // 16 KB
    __shared__ float sW[32][128];   // 16 KB (one 32-row k-tile of W1)

    {   // stage x tile: 1024 float4s, coalesced
        const float4* xg = (const float4*)(x + (size_t)n0 * 128);
#pragma unroll
        for (int i = 0; i < 4; ++i) {
            const int f = t + i * 256;
            ((float4*)sx)[f] = xg[f];
        }
    }

    const int tj = t & 31;          // column group: cols 4*tj .. 4*tj+3
    const int tn = (t >> 5) * 4;    // node group:   nodes tn .. tn+3
    float4 acc[4] = {{0,0,0,0},{0,0,0,0},{0,0,0,0},{0,0,0,0}};

    for (int kt = 0; kt < 128; kt += 32) {
        __syncthreads();
        const float4* wg = (const float4*)(W1 + (size_t)kt * 128);
#pragma unroll
        for (int i = 0; i < 4; ++i) {
            const int f = t + i * 256;
            ((float4*)sW)[f] = wg[f];
        }
        __syncthreads();
        for (int k = 0; k < 32; k += 4) {
            float4 xv[4];
#pragma unroll
            for (int i = 0; i < 4; ++i)
                xv[i] = *(const float4*)&sx[tn + i][kt + k];   // broadcast reads
#pragma unroll
            for (int kk = 0; kk < 4; ++kk) {
                const float4 wv = *(const float4*)&sW[k + kk][tj * 4];
#pragma unroll
                for (int i = 0; i < 4; ++i) {
                    const float xs = ((const float*)&xv[i])[kk];
                    acc[i].x = fmaf(xs, wv.x, acc[i].x);
                    acc[i].y = fmaf(xs, wv.y, acc[i].y);
                    acc[i].z = fmaf(xs, wv.z, acc[i].z);
                    acc[i].w = fmaf(xs, wv.w, acc[i].w);
                }
            }
        }
    }

    // write xw1 as fp16 (4 halves = 8B store, aligned)
#pragma unroll
    for (int i = 0; i < 4; ++i) {
        __half hp[4];
        hp[0] = __float2half(acc[i].x);
        hp[1] = __float2half(acc[i].y);
        hp[2] = __float2half(acc[i].z);
        hp[3] = __float2half(acc[i].w);
        *(uint2*)&xw1h[(size_t)(n0 + tn + i) * 128 + tj * 4] = *(uint2*)hp;
    }

    // fused attention dots (fp32): head h = tj>>3
    const float4 asv = ((const float4*)a_src1)[tj];
    const float4 adv = ((const float4*)a_dst1)[tj];
#pragma unroll
    for (int i = 0; i < 4; ++i) {
        float ps = acc[i].x * asv.x + acc[i].y * asv.y + acc[i].z * asv.z + acc[i].w * asv.w;
        float pd = acc[i].x * adv.x + acc[i].y * adv.y + acc[i].z * adv.z + acc[i].w * adv.w;
#pragma unroll
        for (int o = 1; o < 8; o <<= 1) { ps += __shfl_xor(ps, o, 64); pd += __shfl_xor(pd, o, 64); }
        if ((tj & 7) == 0) {
            const int h = tj >> 3;
            al1[(size_t)(n0 + tn + i) * 4 + h] = ps;
            ar1[(size_t)(n0 + tn + i) * 4 + h] = pd;
        }
    }
}

// ---------------------------------------------------------------------------
// Layer 1 pull-aggregation v3b: one WAVE per dst node, zero barriers.
// Lane = g*16+c: 4 edge-groups x 16 col-lanes; each lane gathers uint4
// (8 halves, 16B) -> one wave-load moves 4 full rows. Weight computed
// inline: al1[s*4+h] is a same-address broadcast across the 16 col lanes
// (al1 = 1.6MB, L2-resident); ar1 term hoisted to a register. 8 edges in
// flight. Shuffle-only reduction; fused /denom + b1 + ReLU, fp16 out.
// ---------------------------------------------------------------------------
__global__ __launch_bounds__(256)
void k_aggr1(const int* __restrict__ ssrc, const int* __restrict__ offs,
             const int* __restrict__ deg, const float* __restrict__ al1,
             const float* __restrict__ ar1, const __half* __restrict__ xw1h,
             const float* __restrict__ b1, __half* __restrict__ out1h) {
    const int lane = threadIdx.x & 63;
    const int d = blockIdx.x * 4 + (threadIdx.x >> 6);
    const int g = lane >> 4;                 // edge group 0..3
    const int c = lane & 15;                 // col group: features 8c..8c+7
    const int h = c >> 2;                    // head of this col group
    const int beg = offs[d];
    const int n = deg[d];
    const float arh = ar1[(size_t)d * 4 + h];
    float acc[8] = {0.f, 0.f, 0.f, 0.f, 0.f, 0.f, 0.f, 0.f};
    float dnm = 0.f;

    for (int base = 0; base < n; base += 8) {
#pragma unroll
        for (int u = 0; u < 2; ++u) {
            const int e = base + u * 4 + g;
            const bool p = e < n;
            const int s = ssrc[beg + (p ? e : 0)];         // L1-hot (sequential)
            float v = al1[(size_t)s * 4 + h] + arh;        // broadcast gather
            v = v > 0.f ? v : NEG_SLOPE * v;
            const float w = p ? __expf(v) : 0.f;
            const uint4 rv = *(const uint4*)&xw1h[(size_t)s * 128 + c * 8];
            const float2 f0 = __half22float2(*(const __half2*)&rv.x);
            const float2 f1 = __half22float2(*(const __half2*)&rv.y);
            const float2 f2 = __half22float2(*(const __half2*)&rv.z);
            const float2 f3 = __half22float2(*(const __half2*)&rv.w);
            acc[0] = fmaf(w, f0.x, acc[0]); acc[1] = fmaf(w, f0.y, acc[1]);
            acc[2] = fmaf(w, f1.x, acc[2]); acc[3] = fmaf(w, f1.y, acc[3]);
            acc[4] = fmaf(w, f2.x, acc[4]); acc[5] = fmaf(w, f2.y, acc[5]);
            acc[6] = fmaf(w, f3.x, acc[6]); acc[7] = fmaf(w, f3.y, acc[7]);
            dnm += w;
        }
    }
    // reduce across the 4 edge-groups (g lives in lane bits 4..5)
#pragma unroll
    for (int i = 0; i < 8; ++i) {
        acc[i] += __shfl_xor(acc[i], 16, 64);
        acc[i] += __shfl_xor(acc[i], 32, 64);
    }
    dnm += __shfl_xor(dnm, 16, 64);
    dnm += __shfl_xor(dnm, 32, 64);
    if (g == 0) {
        const float rc = 1.f / dnm;
        const float4 b01 = *(const float4*)&b1[c * 8];
        const float4 b23 = *(const float4*)&b1[c * 8 + 4];
        const float bb[8] = {b01.x, b01.y, b01.z, b01.w, b23.x, b23.y, b23.z, b23.w};
        __half ho[8];
#pragma unroll
        for (int i = 0; i < 8; ++i) {
            const float hv = acc[i] * rc + bb[i];
            ho[i] = __float2half(hv > 0.f ? hv : 0.f);     // bias + ReLU
        }
        *(uint4*)&out1h[(size_t)d * 128 + c * 8] = *(uint4*)ho;
    }
}

// ---------------------------------------------------------------------------
// Layer 2 GEMM: 16 nodes/block, 256 threads. Reads fp16 out1, fp32 math,
// xw2 stored fp16, al2/ar2 fp32.
// ---------------------------------------------------------------------------
__global__ __launch_bounds__(256)
void k_gemm2(const __half* __restrict__ out1h, const float* __restrict__ W2,
             const float* __restrict__ a_src2, const float* __restrict__ a_dst2,
             __half* __restrict__ xw2h, float* __restrict__ al2, float* __restrict__ ar2) {
    const int t = threadIdx.x;
    const int node0 = blockIdx.x * 16;
    __shared__ float sW[128 * 16];
    __shared__ float sh[16][129];            // +1 pad: kills 4-way bank conflict
    for (int i = t; i < 2048; i += 256) sW[i] = W2[i];
    for (int i = t; i < 2048; i += 256) {
        const int nn = i >> 7, kk = i & 127;
        sh[nn][kk] = __half2float(out1h[(size_t)(node0 + nn) * 128 + kk]);
    }
    __syncthreads();
    const int nn = t >> 4;                   // 0..15
    const int j = t & 15;
    float acc = 0.f;
#pragma unroll 8
    for (int k = 0; k < 128; ++k)
        acc = fmaf(sh[nn][k], sW[k * 16 + j], acc);
    xw2h[(size_t)(node0 + nn) * 16 + j] = __float2half(acc);

    float ps = acc * a_src2[j];
    float pd = acc * a_dst2[j];
#pragma unroll
    for (int o = 8; o; o >>= 1) { ps += __shfl_xor(ps, o, 64); pd += __shfl_xor(pd, o, 64); }
    if (j == 0) { al2[node0 + nn] = ps; ar2[node0 + nn] = pd; }
}

// ---------------------------------------------------------------------------
// Layer 2 pull-aggregation: one wave per node; 8 edge-groups x 8 half2
// feature-lanes. Cross-group shuffle reduction, fused +b2.
// ---------------------------------------------------------------------------
__global__ __launch_bounds__(256)
void k_aggr2(const int* __restrict__ ssrc, const int* __restrict__ offs,
             const int* __restrict__ deg, const float* __restrict__ al2,
             const float* __restrict__ ar2, const __half* __restrict__ xw2h,
             const float* __restrict__ b2, float* __restrict__ out) {
    const int lane = threadIdx.x & 63;
    const int node = blockIdx.x * 4 + (threadIdx.x >> 6);
    const int j2 = lane & 7;                 // feature pair 2*j2, 2*j2+1
    const int eL = lane >> 3;                // 0..7
    const int beg = offs[node];
    const int n = deg[node];
    const float ard = ar2[node];
    float a0 = 0.f, a1 = 0.f, dnm = 0.f;
    for (int base = 0; base < n; base += 8) {
        const int e = base + eL;
        const bool p = e < n;
        const int s = ssrc[beg + (p ? e : 0)];
        float v = al2[s] + ard;
        v = v > 0.f ? v : NEG_SLOPE * v;
        const float w = p ? __expf(v) : 0.f;
        const float2 f = __half22float2(*(const __half2*)&xw2h[(size_t)s * 16 + j2 * 2]);
        a0 = fmaf(w, f.x, a0);
        a1 = fmaf(w, f.y, a1);
        dnm += w;
    }
#pragma unroll
    for (int o = 8; o < 64; o <<= 1) {
        a0 += __shfl_xor(a0, o, 64);
        a1 += __shfl_xor(a1, o, 64);
        dnm += __shfl_xor(dnm, o, 64);
    }
    if (eL == 0) {
        out[(size_t)node * 16 + j2 * 2]     = a0 / dnm + b2[j2 * 2];
        out[(size_t)node * 16 + j2 * 2 + 1] = a1 / dnm + b2[j2 * 2 + 1];
    }
}

extern "C" void kernel_launch(void* const* d_in, const int* in_sizes, int n_in,
                              void* d_out, int out_size, void* d_ws, size_t ws_size,
                              hipStream_t stream) {
    const float* x      = (const float*)d_in[0];
    const int*   ei     = (const int*)d_in[1];
    const float* W1     = (const float*)d_in[2];
    const float* a_src1 = (const float*)d_in[3];
    const float* a_dst1 = (const float*)d_in[4];
    const float* b1     = (const float*)d_in[5];
    const float* W2     = (const float*)d_in[6];
    const float* a_src2 = (const float*)d_in[7];
    const float* a_dst2 = (const float*)d_in[8];
    const float* b2     = (const float*)d_in[9];
    float* out = (float*)d_out;

    // Workspace (byte-addressed). Aliases:
    //  - pairs (18.9MB) sits in out1h's region (25.6MB): consumed by k_fill2
    //    before k_aggr1 writes out1h.
    //  - xw2h/al2/ar2 sit in xw1h's region: written by k_gemm2 after k_aggr1
    //    is done with xw1h.
    char* wsb = (char*)d_ws;
    __half* xw1h = (__half*)wsb;                                  // N*128 half (25.6 MB)
    __half* xw2h = (__half*)wsb;                                  // N*16 half (alias)
    float*  al2  = (float*)(wsb + (size_t)N_NODES * 16 * 2);      // N fp32 (alias)
    float*  ar2  = al2 + N_NODES;                                 // N fp32 (alias)
    __half* out1h = (__half*)(wsb + (size_t)N_NODES * 128 * 2);   // N*128 half (25.6 MB)
    int2*   pairs = (int2*)out1h;                                 // 128*BSTRIDE int2 (alias, 18.9 MB)
    float*  al1  = (float*)(wsb + (size_t)N_NODES * 128 * 4);     // N*4 fp32
    float*  ar1  = al1 + (size_t)N_NODES * 4;                     // N*4
    int* ideg  = (int*)(ar1 + (size_t)N_NODES * 4);               // N      } zeroed together
    int* ibcnt = ideg + N_NODES;                                  // 128    } zeroed together
    int* ioff  = ibcnt + 128;                                     // N
    int* icur  = ioff + N_NODES;                                  // N
    int* ibs   = icur + N_NODES;                                  // 512
    int* isrc  = ibs + 512;                                       // E_TOT

    hipMemsetAsync(ideg, 0, ((size_t)N_NODES + 128) * sizeof(int), stream);

    // CSR build: part (deg histogram + bucket partition) -> scan -> fill.
    k_part<<<(E_TOT + PART_EPB - 1) / PART_EPB, 256, 0, stream>>>(ei, ideg, ibcnt, pairs);
    k_scan1<<<NB1, 256, 0, stream>>>(ideg, ioff, ibs);
    k_scan2<<<1, 512, 0, stream>>>(ibs);
    k_scan3<<<NB1, 256, 0, stream>>>(ioff, ibs, icur);
    k_fill2<<<128 * FILL_CPB, 256, 0, stream>>>(pairs, ibcnt, icur, isrc);

    // Layer 1
    k_gemm1<<<N_NODES / 32, 256, 0, stream>>>(x, W1, a_src1, a_dst1, xw1h, al1, ar1);
    k_aggr1<<<N_NODES / 4, 256, 0, stream>>>(isrc, ioff, ideg, al1, ar1, xw1h, b1, out1h);

    // Layer 2
    k_gemm2<<<N_NODES / 16, 256, 0, stream>>>(out1h, W2, a_src2, a_dst2, xw2h, al2, ar2);
    k_aggr2<<<N_NODES / 4, 256, 0, stream>>>(isrc, ioff, ideg, al2, ar2, xw2h, b2, out);
}

// Round 9
// 356.741 us; speedup vs baseline: 1.5541x; 1.5328x over previous
//
#include <hip/hip_runtime.h>
#include <hip/hip_fp16.h>

#define N_NODES 100000
#define N_EDGES 1600000
#define E_TOT   (N_EDGES + N_NODES)   // 1,700,000 incl. self-loops
#define NEG_SLOPE 0.2f
#define PART_EPB 4096                 // edges per k_part block
#define BSTRIDE 18432                 // slots per bucket region (mean 17408 + 7.8 sigma; fixed input -> deterministic)

// ---------------------------------------------------------------------------
// k_part: partition edges into 128 fixed-stride dst-buckets (dst>>10).
// Only global atomics left in the pipeline: one per (block,bucket) to
// reserve a contiguous range (~128 * 416 total). R8 post-mortem: the 1.7M
// scattered global atomics (deg histogram + fill cursors) were the 155us
// bottleneck -> replaced by per-bucket LDS counting sort (k_fill3).
// ---------------------------------------------------------------------------
__global__ __launch_bounds__(256)
void k_part(const int* __restrict__ ei, int* __restrict__ bcnt, int2* __restrict__ pairs) {
    const int t = threadIdx.x;
    const int base = blockIdx.x * PART_EPB;
    __shared__ int lcnt[128];
    __shared__ int lbase[128];
    if (t < 128) lcnt[t] = 0;
    __syncthreads();
    int sr[16], dr[16];
#pragma unroll
    for (int u = 0; u < 16; ++u) {
        const int e = base + u * 256 + t;    // coalesced
        if (e < E_TOT) {
            int s, d;
            if (e < N_EDGES) { s = ei[e]; d = ei[N_EDGES + e]; }
            else             { s = d = e - N_EDGES; }
            sr[u] = s; dr[u] = d;
            atomicAdd(&lcnt[d >> 10], 1);    // LDS
        } else dr[u] = -1;
    }
    __syncthreads();
    if (t < 128) {
        const int c = lcnt[t];
        lbase[t] = (c > 0) ? atomicAdd(&bcnt[t], c) : 0;   // global, 1 per bucket
        lcnt[t] = 0;                         // reuse as local cursor
    }
    __syncthreads();
#pragma unroll
    for (int u = 0; u < 16; ++u) {
        if (dr[u] >= 0) {
            const int bk = dr[u] >> 10;
            const int r = atomicAdd(&lcnt[bk], 1);         // LDS
            pairs[(size_t)bk * BSTRIDE + lbase[bk] + r] = make_int2(sr[u], dr[u]);
        }
    }
}

// ---------------------------------------------------------------------------
// k_fill3: one 1024-thread block per bucket. Per-bucket counting sort with
// LDS histogram + LDS cursors — zero global atomics. Because buckets are
// node-ordered, sbase + local exclusive prefix IS the global CSR offset, so
// this kernel also produces ioff and deg (replaces scan1/2/3 entirely).
// The block owns its bucket's ssrc span exclusively -> writes stay in one
// XCD's L2 and flush as full lines.
// ---------------------------------------------------------------------------
__global__ __launch_bounds__(1024)
void k_fill3(const int2* __restrict__ pairs, const int* __restrict__ bcnt,
             int* __restrict__ ioff, int* __restrict__ deg, int* __restrict__ ssrc) {
    const int bucket = blockIdx.x;
    const int t = threadIdx.x;
    const int cnt = bcnt[bucket];
    __shared__ int lhist[1024];
    __shared__ int lcur[1024];
    __shared__ int wsum[16];
    __shared__ int sbase;
    lhist[t] = 0;
    if (t == 0) {                            // edges to all lower buckets
        int b = 0;
        for (int k = 0; k < bucket; ++k) b += bcnt[k];
        sbase = b;
    }
    __syncthreads();
    // Phase A: LDS histogram of local dst
    for (int i = t; i < cnt; i += 1024) {
        const int2 p = pairs[(size_t)bucket * BSTRIDE + i];
        atomicAdd(&lhist[p.y & 1023], 1);
    }
    __syncthreads();
    // Phase B: block-level scan (wave shfl scan + wave-sum scan)
    const int v = lhist[t];
    int inc = v;
    const int lane = t & 63, wid = t >> 6;
#pragma unroll
    for (int o = 1; o < 64; o <<= 1) {
        const int nv = __shfl_up(inc, o, 64);
        if (lane >= o) inc += nv;
    }
    if (lane == 63) wsum[wid] = inc;
    __syncthreads();
    if (t == 0) {
        int acc = 0;
#pragma unroll
        for (int k = 0; k < 16; ++k) { const int tv = wsum[k]; wsum[k] = acc; acc += tv; }
    }
    __syncthreads();
    const int gofs = sbase + (inc - v) + wsum[wid];   // global CSR offset of node d
    const int d = bucket * 1024 + t;
    if (d < N_NODES) { ioff[d] = gofs; deg[d] = v; }  // coalesced, no atomics
    lcur[t] = gofs;
    __syncthreads();
    // Phase C: place edges via LDS cursors
    for (int i = t; i < cnt; i += 1024) {
        const int2 p = pairs[(size_t)bucket * BSTRIDE + i];
        const int pos = atomicAdd(&lcur[p.y & 1023], 1);   // LDS
        ssrc[pos] = p.x;
    }
}

// ---------------------------------------------------------------------------
// Layer 1 GEMM, register-tiled: 256 threads, 32 nodes/block, 4x4 tile/thread.
// fp32 math; xw1 stored fp16.
// ---------------------------------------------------------------------------
__global__ __launch_bounds__(256)
void k_gemm1(const float* __restrict__ x, const float* __restrict__ W1,
             const float* __restrict__ a_src1, const float* __restrict__ a_dst1,
             __half* __restrict__ xw1h, float* __restrict__ al1, float* __restrict__ ar1) {
    const int t = threadIdx.x;
    const int n0 = blockIdx.x * 32;
    __shared__ float sx[32][128];   // 16 KB
    __shared__ float sW[32][128];   // 16 KB (one 32-row k-tile of W1)

    {   // stage x tile: 1024 float4s, coalesced
        const float4* xg = (const float4*)(x + (size_t)n0 * 128);
#pragma unroll
        for (int i = 0; i < 4; ++i) {
            const int f = t + i * 256;
            ((float4*)sx)[f] = xg[f];
        }
    }

    const int tj = t & 31;          // column group: cols 4*tj .. 4*tj+3
    const int tn = (t >> 5) * 4;    // node group:   nodes tn .. tn+3
    float4 acc[4] = {{0,0,0,0},{0,0,0,0},{0,0,0,0},{0,0,0,0}};

    for (int kt = 0; kt < 128; kt += 32) {
        __syncthreads();
        const float4* wg = (const float4*)(W1 + (size_t)kt * 128);
#pragma unroll
        for (int i = 0; i < 4; ++i) {
            const int f = t + i * 256;
            ((float4*)sW)[f] = wg[f];
        }
        __syncthreads();
        for (int k = 0; k < 32; k += 4) {
            float4 xv[4];
#pragma unroll
            for (int i = 0; i < 4; ++i)
                xv[i] = *(const float4*)&sx[tn + i][kt + k];   // broadcast reads
#pragma unroll
            for (int kk = 0; kk < 4; ++kk) {
                const float4 wv = *(const float4*)&sW[k + kk][tj * 4];
#pragma unroll
                for (int i = 0; i < 4; ++i) {
                    const float xs = ((const float*)&xv[i])[kk];
                    acc[i].x = fmaf(xs, wv.x, acc[i].x);
                    acc[i].y = fmaf(xs, wv.y, acc[i].y);
                    acc[i].z = fmaf(xs, wv.z, acc[i].z);
                    acc[i].w = fmaf(xs, wv.w, acc[i].w);
                }
            }
        }
    }

    // write xw1 as fp16 (4 halves = 8B store, aligned)
#pragma unroll
    for (int i = 0; i < 4; ++i) {
        __half hp[4];
        hp[0] = __float2half(acc[i].x);
        hp[1] = __float2half(acc[i].y);
        hp[2] = __float2half(acc[i].z);
        hp[3] = __float2half(acc[i].w);
        *(uint2*)&xw1h[(size_t)(n0 + tn + i) * 128 + tj * 4] = *(uint2*)hp;
    }

    // fused attention dots (fp32): head h = tj>>3
    const float4 asv = ((const float4*)a_src1)[tj];
    const float4 adv = ((const float4*)a_dst1)[tj];
#pragma unroll
    for (int i = 0; i < 4; ++i) {
        float ps = acc[i].x * asv.x + acc[i].y * asv.y + acc[i].z * asv.z + acc[i].w * asv.w;
        float pd = acc[i].x * adv.x + acc[i].y * adv.y + acc[i].z * adv.z + acc[i].w * adv.w;
#pragma unroll
        for (int o = 1; o < 8; o <<= 1) { ps += __shfl_xor(ps, o, 64); pd += __shfl_xor(pd, o, 64); }
        if ((tj & 7) == 0) {
            const int h = tj >> 3;
            al1[(size_t)(n0 + tn + i) * 4 + h] = ps;
            ar1[(size_t)(n0 + tn + i) * 4 + h] = pd;
        }
    }
}

// ---------------------------------------------------------------------------
// Layer 1 pull-aggregation: one WAVE per dst node, zero barriers.
// Lane = g*16+c: 4 edge-groups x 16 col-lanes; uint4 gathers (4 rows per
// wave-load), inline weight (al1 broadcast gather + expf), 8 edges in
// flight. Shuffle reduction; fused /denom + b1 + ReLU, fp16 out.
// ---------------------------------------------------------------------------
__global__ __launch_bounds__(256)
void k_aggr1(const int* __restrict__ ssrc, const int* __restrict__ offs,
             const int* __restrict__ deg, const float* __restrict__ al1,
             const float* __restrict__ ar1, const __half* __restrict__ xw1h,
             const float* __restrict__ b1, __half* __restrict__ out1h) {
    const int lane = threadIdx.x & 63;
    const int d = blockIdx.x * 4 + (threadIdx.x >> 6);
    const int g = lane >> 4;                 // edge group 0..3
    const int c = lane & 15;                 // col group: features 8c..8c+7
    const int h = c >> 2;                    // head of this col group
    const int beg = offs[d];
    const int n = deg[d];
    const float arh = ar1[(size_t)d * 4 + h];
    float acc[8] = {0.f, 0.f, 0.f, 0.f, 0.f, 0.f, 0.f, 0.f};
    float dnm = 0.f;

    for (int base = 0; base < n; base += 8) {
#pragma unroll
        for (int u = 0; u < 2; ++u) {
            const int e = base + u * 4 + g;
            const bool p = e < n;
            const int s = ssrc[beg + (p ? e : 0)];         // L1-hot (sequential)
            float v = al1[(size_t)s * 4 + h] + arh;        // broadcast gather
            v = v > 0.f ? v : NEG_SLOPE * v;
            const float w = p ? __expf(v) : 0.f;
            const uint4 rv = *(const uint4*)&xw1h[(size_t)s * 128 + c * 8];
            const float2 f0 = __half22float2(*(const __half2*)&rv.x);
            const float2 f1 = __half22float2(*(const __half2*)&rv.y);
            const float2 f2 = __half22float2(*(const __half2*)&rv.z);
            const float2 f3 = __half22float2(*(const __half2*)&rv.w);
            acc[0] = fmaf(w, f0.x, acc[0]); acc[1] = fmaf(w, f0.y, acc[1]);
            acc[2] = fmaf(w, f1.x, acc[2]); acc[3] = fmaf(w, f1.y, acc[3]);
            acc[4] = fmaf(w, f2.x, acc[4]); acc[5] = fmaf(w, f2.y, acc[5]);
            acc[6] = fmaf(w, f3.x, acc[6]); acc[7] = fmaf(w, f3.y, acc[7]);
            dnm += w;
        }
    }
#pragma unroll
    for (int i = 0; i < 8; ++i) {
        acc[i] += __shfl_xor(acc[i], 16, 64);
        acc[i] += __shfl_xor(acc[i], 32, 64);
    }
    dnm += __shfl_xor(dnm, 16, 64);
    dnm += __shfl_xor(dnm, 32, 64);
    if (g == 0) {
        const float rc = 1.f / dnm;
        const float4 b01 = *(const float4*)&b1[c * 8];
        const float4 b23 = *(const float4*)&b1[c * 8 + 4];
        const float bb[8] = {b01.x, b01.y, b01.z, b01.w, b23.x, b23.y, b23.z, b23.w};
        __half ho[8];
#pragma unroll
        for (int i = 0; i < 8; ++i) {
            const float hv = acc[i] * rc + bb[i];
            ho[i] = __float2half(hv > 0.f ? hv : 0.f);     // bias + ReLU
        }
        *(uint4*)&out1h[(size_t)d * 128 + c * 8] = *(uint4*)ho;
    }
}

// ---------------------------------------------------------------------------
// Layer 2 GEMM: 16 nodes/block, 256 threads. Reads fp16 out1, fp32 math,
// xw2 stored fp16, al2/ar2 fp32.
// ---------------------------------------------------------------------------
__global__ __launch_bounds__(256)
void k_gemm2(const __half* __restrict__ out1h, const float* __restrict__ W2,
             const float* __restrict__ a_src2, const float* __restrict__ a_dst2,
             __half* __restrict__ xw2h, float* __restrict__ al2, float* __restrict__ ar2) {
    const int t = threadIdx.x;
    const int node0 = blockIdx.x * 16;
    __shared__ float sW[128 * 16];
    __shared__ float sh[16][129];            // +1 pad: kills 4-way bank conflict
    for (int i = t; i < 2048; i += 256) sW[i] = W2[i];
    for (int i = t; i < 2048; i += 256) {
        const int nn = i >> 7, kk = i & 127;
        sh[nn][kk] = __half2float(out1h[(size_t)(node0 + nn) * 128 + kk]);
    }
    __syncthreads();
    const int nn = t >> 4;                   // 0..15
    const int j = t & 15;
    float acc = 0.f;
#pragma unroll 8
    for (int k = 0; k < 128; ++k)
        acc = fmaf(sh[nn][k], sW[k * 16 + j], acc);
    xw2h[(size_t)(node0 + nn) * 16 + j] = __float2half(acc);

    float ps = acc * a_src2[j];
    float pd = acc * a_dst2[j];
#pragma unroll
    for (int o = 8; o; o >>= 1) { ps += __shfl_xor(ps, o, 64); pd += __shfl_xor(pd, o, 64); }
    if (j == 0) { al2[node0 + nn] = ps; ar2[node0 + nn] = pd; }
}

// ---------------------------------------------------------------------------
// Layer 2 pull-aggregation: one wave per node; 8 edge-groups x 8 half2
// feature-lanes. Cross-group shuffle reduction, fused +b2.
// ---------------------------------------------------------------------------
__global__ __launch_bounds__(256)
void k_aggr2(const int* __restrict__ ssrc, const int* __restrict__ offs,
             const int* __restrict__ deg, const float* __restrict__ al2,
             const float* __restrict__ ar2, const __half* __restrict__ xw2h,
             const float* __restrict__ b2, float* __restrict__ out) {
    const int lane = threadIdx.x & 63;
    const int node = blockIdx.x * 4 + (threadIdx.x >> 6);
    const int j2 = lane & 7;                 // feature pair 2*j2, 2*j2+1
    const int eL = lane >> 3;                // 0..7
    const int beg = offs[node];
    const int n = deg[node];
    const float ard = ar2[node];
    float a0 = 0.f, a1 = 0.f, dnm = 0.f;
    for (int base = 0; base < n; base += 8) {
        const int e = base + eL;
        const bool p = e < n;
        const int s = ssrc[beg + (p ? e : 0)];
        float v = al2[s] + ard;
        v = v > 0.f ? v : NEG_SLOPE * v;
        const float w = p ? __expf(v) : 0.f;
        const float2 f = __half22float2(*(const __half2*)&xw2h[(size_t)s * 16 + j2 * 2]);
        a0 = fmaf(w, f.x, a0);
        a1 = fmaf(w, f.y, a1);
        dnm += w;
    }
#pragma unroll
    for (int o = 8; o < 64; o <<= 1) {
        a0 += __shfl_xor(a0, o, 64);
        a1 += __shfl_xor(a1, o, 64);
        dnm += __shfl_xor(dnm, o, 64);
    }
    if (eL == 0) {
        out[(size_t)node * 16 + j2 * 2]     = a0 / dnm + b2[j2 * 2];
        out[(size_t)node * 16 + j2 * 2 + 1] = a1 / dnm + b2[j2 * 2 + 1];
    }
}

extern "C" void kernel_launch(void* const* d_in, const int* in_sizes, int n_in,
                              void* d_out, int out_size, void* d_ws, size_t ws_size,
                              hipStream_t stream) {
    const float* x      = (const float*)d_in[0];
    const int*   ei     = (const int*)d_in[1];
    const float* W1     = (const float*)d_in[2];
    const float* a_src1 = (const float*)d_in[3];
    const float* a_dst1 = (const float*)d_in[4];
    const float* b1     = (const float*)d_in[5];
    const float* W2     = (const float*)d_in[6];
    const float* a_src2 = (const float*)d_in[7];
    const float* a_dst2 = (const float*)d_in[8];
    const float* b2     = (const float*)d_in[9];
    float* out = (float*)d_out;

    // Workspace (byte-addressed). Aliases:
    //  - pairs (18.9MB) sits in out1h's region (25.6MB): consumed by k_fill3
    //    before k_aggr1 writes out1h.
    //  - xw2h/al2/ar2 sit in xw1h's region: written by k_gemm2 after k_aggr1
    //    is done with xw1h.
    char* wsb = (char*)d_ws;
    __half* xw1h = (__half*)wsb;                                  // N*128 half (25.6 MB)
    __half* xw2h = (__half*)wsb;                                  // N*16 half (alias)
    float*  al2  = (float*)(wsb + (size_t)N_NODES * 16 * 2);      // N fp32 (alias)
    float*  ar2  = al2 + N_NODES;                                 // N fp32 (alias)
    __half* out1h = (__half*)(wsb + (size_t)N_NODES * 128 * 2);   // N*128 half (25.6 MB)
    int2*   pairs = (int2*)out1h;                                 // 128*BSTRIDE int2 (alias, 18.9 MB)
    float*  al1  = (float*)(wsb + (size_t)N_NODES * 128 * 4);     // N*4 fp32
    float*  ar1  = al1 + (size_t)N_NODES * 4;                     // N*4
    int* ibcnt = (int*)(ar1 + (size_t)N_NODES * 4);               // 128 (zeroed)
    int* ioff  = ibcnt + 128;                                     // N
    int* ideg  = ioff + N_NODES;                                  // N
    int* isrc  = ideg + N_NODES;                                  // E_TOT

    hipMemsetAsync(ibcnt, 0, 128 * sizeof(int), stream);

    // CSR build: bucket partition -> per-bucket counting sort (no scans,
    // no scattered global atomics).
    k_part<<<(E_TOT + PART_EPB - 1) / PART_EPB, 256, 0, stream>>>(ei, ibcnt, pairs);
    k_fill3<<<128, 1024, 0, stream>>>(pairs, ibcnt, ioff, ideg, isrc);

    // Layer 1
    k_gemm1<<<N_NODES / 32, 256, 0, stream>>>(x, W1, a_src1, a_dst1, xw1h, al1, ar1);
    k_aggr1<<<N_NODES / 4, 256, 0, stream>>>(isrc, ioff, ideg, al1, ar1, xw1h, b1, out1h);

    // Layer 2
    k_gemm2<<<N_NODES / 16, 256, 0, stream>>>(out1h, W2, a_src2, a_dst2, xw2h, al2, ar2);
    k_aggr2<<<N_NODES / 4, 256, 0, stream>>>(isrc, ioff, ideg, al2, ar2, xw2h, b2, out);
}